// Round 8
// baseline (313.998 us; speedup 1.0000x reference)
//
#include <hip/hip_runtime.h>
#include <stdint.h>

typedef unsigned int u32;
typedef unsigned long long u64;

#define BB 16
#define NN 25200
#define ROWLEN 85
#define KCAND 1024
#define MAXDET 1000
#define CONF_T 0.25f
#define IOU_T 0.45f
#define MAX_WH 4096.0f
#define KBASE 0xBE800000u    // f2key(0.25f); valid ranks r = key-KBASE in [1, 0xFFFFFF]
#define NHBIN 65536

__device__ __forceinline__ u32 f2key(float f) {
  u32 u = __float_as_uint(f);
  return (u & 0x80000000u) ? ~u : (u | 0x80000000u);
}
__device__ __forceinline__ float key2f(u32 k) {
  u32 u = (k & 0x80000000u) ? (k & 0x7FFFFFFFu) : ~k;
  return __uint_as_float(u);
}

// ---------------- K0: zero the 16x65536 u32 histogram (4 MB) ------------------------
__global__ __launch_bounds__(1024) void k_zero(uint4* __restrict__ histv) {
  histv[(size_t)blockIdx.x * 1024 + threadIdx.x] = make_uint4(0, 0, 0, 0);
}

// ---------------- K1: row reduce + fused global histogram ---------------------------
__global__ __launch_bounds__(64) void k_score(const float* __restrict__ pred,
                                              float* __restrict__ masked,
                                              int* __restrict__ clsArr,
                                              u32* __restrict__ hist) {
  __shared__ float sh[64 * ROWLEN];          // 21760 B -> 7 blocks/CU
  const int t = threadIdx.x;
  const size_t blk = (size_t)blockIdx.x;
  const float4* src = (const float4*)(pred + blk * (64 * ROWLEN));
  float4* dst = (float4*)sh;
  #pragma unroll
  for (int i = 0; i < 21; ++i) dst[t + 64 * i] = src[t + 64 * i];
  if (t < 16) dst[t + 64 * 21] = src[t + 64 * 21];
  __syncthreads();
  const float* row = sh + t * ROWLEN;
  float obj = row[4];
  float v0 = -INFINITY, v1 = -INFINITY, v2 = -INFINITY, v3 = -INFINITY;
  int j0 = 0, j1 = 20, j2 = 40, j3 = 60;
  #pragma unroll
  for (int c = 0; c < 20; ++c) {
    float s0 = obj * row[5 + c];
    float s1 = obj * row[25 + c];
    float s2 = obj * row[45 + c];
    float s3 = obj * row[65 + c];
    if (s0 > v0) { v0 = s0; j0 = c; }
    if (s1 > v1) { v1 = s1; j1 = 20 + c; }
    if (s2 > v2) { v2 = s2; j2 = 40 + c; }
    if (s3 > v3) { v3 = s3; j3 = 60 + c; }
  }
  float v = v0; int j = j0;
  if (v1 > v) { v = v1; j = j1; }
  if (v2 > v) { v = v2; j = j2; }
  if (v3 > v) { v = v3; j = j3; }
  size_t r = blk * 64 + t;
  bool valid = (v > CONF_T);
  masked[r] = valid ? v : -1.0f;
  clsArr[r] = j;
  if (valid) {
    u32 b = (u32)(r / NN);
    u32 rk = f2key(v) - KBASE;                 // [1, 0xFFFFFF]
    atomicAdd(&hist[(size_t)b * NHBIN + (rk >> 8)], 1u);
  }
}

// ---- bitonic helper ----
__device__ __forceinline__ void bt_apply(u64& e, u64 p, int m, int j, int k) {
  bool lower = ((m & j) == 0);
  bool dir = ((m & k) == 0);
  bool takeMax = (lower == dir);
  u64 mx = e > p ? e : p;
  u64 mn = e > p ? p : e;
  e = takeMax ? mx : mn;
}

// -------- K2: coarse threshold from 16-bit-bin histogram + compact + exact sort -----
// T = P<<8 where suffix count crosses 1024; compact r>=T yields 1024..~1027 entries
// (bin occupancy at the cut ~0.4); the (r,~idx) bitonic sort of 2048 resolves the
// exact stable top-1024. Invalid rows have r=0 < T (T>=1), never selected.
__global__ __launch_bounds__(1024, 4) void k_select(const float* __restrict__ pred,
                                                    const float* __restrict__ masked,
                                                    const int* __restrict__ clsArr,
                                                    const u32* __restrict__ hist,
                                                    float* __restrict__ candScore,
                                                    float* __restrict__ candBox,
                                                    int* __restrict__ candCls) {
  __shared__ u64 buf[2048];
  __shared__ u32 waveTot[16];
  __shared__ u32 sh_base, sh_snext, sh_T, sh_cnt;
  const int b = blockIdx.x;
  const int tid = threadIdx.x;
  const int lane = tid & 63;
  const int wv = tid >> 6;
  const u32* hb = hist + (size_t)b * NHBIN;
  const float* m = masked + (size_t)b * NN;

  // prefetch scores (issued together, pipelined)
  float vals[25];
  #pragma unroll
  for (int it = 0; it < 25; ++it) {
    int n0 = tid + it * 1024;
    vals[it] = (n0 < NN) ? m[n0] : -1.0f;
  }

  // ---- threshold: 2-level suffix scan over 65536 bins ----
  u32 sloc = 0;
  const int base = tid * 64;
  for (int i = 0; i < 64; ++i) sloc += hb[base + i];
  u32 incl = sloc;
  #pragma unroll
  for (int off = 1; off <= 32; off <<= 1) {
    u32 o = __shfl_down(incl, off, 64);
    if (lane + off < 64) incl += o;
  }
  if (lane == 0) waveTot[wv] = incl;    // suffix within wave starts at its chunk 0
  __syncthreads();
  u32 wsuf = 0;
  for (int w = wv + 1; w < 16; ++w) wsuf += waveTot[w];
  u32 S_t = incl + wsuf;                // sum of bins >= base
  u32 S_n = S_t - sloc;                 // sum of bins >= base+64
  if (S_t >= KCAND && S_n < KCAND) { sh_base = (u32)base; sh_snext = S_n; }
  if (tid == 0) sh_cnt = 0;
  __syncthreads();
  if (wv == 0) {
    u32 bv = hb[sh_base + lane];
    u32 suf = bv;
    #pragma unroll
    for (int off = 1; off <= 32; off <<= 1) {
      u32 o = __shfl_down(suf, off, 64);
      if (lane + off < 64) suf += o;
    }
    u32 Sl = suf + sh_snext;            // sum of bins >= sh_base+lane
    u32 Snl = Sl - bv;
    if (Sl >= KCAND && Snl < KCAND) {
      u32 tt = (sh_base + lane) << 8;
      sh_T = tt ? tt : 1u;
    }
  }
  __syncthreads();
  const u32 T = sh_T;

  // ---- compact r >= T (ballot-aggregated) ----
  #pragma unroll
  for (int it = 0; it < 25; ++it) {
    int n0 = tid + it * 1024;
    float val = vals[it];
    u32 r = (val > 0.0f) ? (f2key(val) - KBASE) : 0u;
    bool match = (r >= T);
    u64 bal = __ballot(match);
    if (bal) {
      int leader = __ffsll((unsigned long long)bal) - 1;
      u32 bpos = 0;
      u32 cnt = (u32)__popcll(bal);
      if (lane == leader) bpos = atomicAdd(&sh_cnt, cnt);
      bpos = __shfl(bpos, leader, 64);
      if (match) {
        u32 pos = bpos + (u32)__popcll(bal & ((1ull << lane) - 1ull));
        if (pos < 2048) buf[pos] = ((u64)r << 32) | (u32)(~(u32)n0);
      }
    }
  }
  __syncthreads();
  u32 c = sh_cnt; if (c > 2048) c = 2048;
  for (int t2 = tid; t2 < 2048; t2 += 1024) if (t2 >= (int)c) buf[t2] = 0;
  __syncthreads();

  // ---- hybrid bitonic sort desc on (r, ~idx) ----
  u64 e0 = buf[tid];
  u64 e1 = buf[tid + 1024];
  #pragma unroll
  for (int k = 2; k <= 64; k <<= 1) {
    #pragma unroll
    for (int j = k >> 1; j > 0; j >>= 1) {
      u64 p0 = __shfl_xor(e0, j, 64);
      u64 p1 = __shfl_xor(e1, j, 64);
      bt_apply(e0, p0, tid, j, k);
      bt_apply(e1, p1, tid + 1024, j, k);
    }
  }
  for (int k = 128; k <= 2048; k <<= 1) {
    int jstart = k >> 1;
    if (k == 2048) {
      u64 mx = e0 > e1 ? e0 : e1;
      u64 mn = e0 > e1 ? e1 : e0;
      e0 = mx; e1 = mn;
      jstart = 512;
    }
    for (int j = jstart; j >= 64; j >>= 1) {
      buf[tid] = e0; buf[tid + 1024] = e1;
      __syncthreads();
      u64 p0 = buf[tid ^ j];
      u64 p1 = buf[(tid ^ j) + 1024];
      bt_apply(e0, p0, tid, j, k);
      bt_apply(e1, p1, tid + 1024, j, k);
      __syncthreads();
    }
    #pragma unroll
    for (int j = 32; j > 0; j >>= 1) {
      u64 p0 = __shfl_xor(e0, j, 64);
      u64 p1 = __shfl_xor(e1, j, 64);
      bt_apply(e0, p0, tid, j, k);
      bt_apply(e1, p1, tid + 1024, j, k);
    }
  }
  {
    u64 e = e0;
    u32 r = (u32)(e >> 32);
    u32 idx = ~(u32)e;
    if (idx >= NN) idx = 0;
    float sc = key2f(r + KBASE);
    size_t g = (size_t)b * KCAND + tid;
    candScore[g] = sc;
    const float* p = pred + ((size_t)b * NN + idx) * ROWLEN;
    float cx = p[0], cy = p[1], w = p[2], h = p[3];
    float4 bx;
    bx.x = cx - 0.5f * w;
    bx.y = cy - 0.5f * h;
    bx.z = cx + 0.5f * w;
    bx.w = cy + 0.5f * h;
    ((float4*)candBox)[g] = bx;
    candCls[g] = clsArr[(size_t)b * NN + idx];
  }
}

// ---------------- K3a: 1024x1024 IoU>thr bitmask, TRANSPOSED layout matT[b][w][row] --
__global__ __launch_bounds__(256) void k_iou(const float* __restrict__ candBox,
                                             const int* __restrict__ candCls,
                                             u64* __restrict__ matT) {
  #pragma clang fp contract(off)
  __shared__ float sx1[KCAND], sy1[KCAND], sx2[KCAND], sy2[KCAND], sar[KCAND];
  const int b = blockIdx.y;
  const int r0 = blockIdx.x * 64;
  const int tid = threadIdx.x;
  for (int i = tid; i < KCAND; i += 256) {
    float4 bx = ((const float4*)candBox)[(size_t)b * KCAND + i];
    float off = (float)candCls[(size_t)b * KCAND + i] * MAX_WH;
    float x1 = bx.x + off, y1 = bx.y + off, x2 = bx.z + off, y2 = bx.w + off;
    sx1[i] = x1; sy1[i] = y1; sx2[i] = x2; sy2[i] = y2;
    sar[i] = (x2 - x1) * (y2 - y1);
  }
  __syncthreads();
  const int row = r0 + (tid & 63);
  const int wbase = tid >> 6;
  float rx1 = sx1[row], ry1 = sy1[row], rx2 = sx2[row], ry2 = sy2[row], rar = sar[row];
  for (int q = 0; q < 4; ++q) {
    int w = wbase + q * 4;
    int jb = w << 6;
    u64 mk = 0;
    for (int kk = 0; kk < 64; ++kk) {
      int jj = jb + kk;
      float ix1 = fmaxf(rx1, sx1[jj]);
      float iy1 = fmaxf(ry1, sy1[jj]);
      float ix2 = fminf(rx2, sx2[jj]);
      float iy2 = fminf(ry2, sy2[jj]);
      float dx = fmaxf(ix2 - ix1, 0.0f);
      float dy = fmaxf(iy2 - iy1, 0.0f);
      float inter = dx * dy;
      float den = rar + sar[jj];
      den = den - inter;
      den = den + 1e-9f;
      float iou = inter / den;
      if (iou > IOU_T) mk |= (1ull << kk);
    }
    matT[(((size_t)b * 16 + w) << 10) + row] = mk;
  }
}

// -------- K3b (fused scan + output): ENTIRE lower triangle in wave-0 registers ------
#define TRIDX(c, cp) (((c) * ((c)-1)) / 2 + (cp))
__global__ __launch_bounds__(256, 1) void k_scan_out(const u64* __restrict__ matT,
                                                     const float* __restrict__ candScore,
                                                     const float* __restrict__ candBox,
                                                     const int* __restrict__ candCls,
                                                     float* __restrict__ out) {
  __shared__ u64 sKeep[16];
  const int b = blockIdx.x;
  const int tid = threadIdx.x;
  const u64* Mb = matT + ((size_t)b << 14);

  if (tid < 64) {
    const int lane = tid;
    u64 vw[16], dg[16], tri[120], kcw[16];
    #pragma unroll
    for (int w = 0; w < 16; ++w) {
      float sc = candScore[(size_t)b * KCAND + w * 64 + lane];
      vw[w] = __ballot(sc > 0.0f);
    }
    #pragma unroll
    for (int c = 0; c < 16; ++c)
      dg[c] = Mb[((size_t)c << 10) + c * 64 + lane];
    #pragma unroll
    for (int c = 1; c < 16; ++c) {
      #pragma unroll
      for (int cp = 0; cp < c; ++cp)
        tri[TRIDX(c, cp)] = Mb[((size_t)c << 10) + cp * 64 + lane];
    }

    #pragma unroll
    for (int c = 0; c < 16; ++c) {
      u64 acc = 0;
      #pragma unroll
      for (int cp = 0; cp < 15; ++cp) {
        if (cp < c) {
          if ((kcw[cp] >> lane) & 1ull) acc |= tri[TRIDX(c, cp)];
        }
      }
      #pragma unroll
      for (int st = 1; st < 64; st <<= 1) acc |= __shfl_xor(acc, st, 64);
      u64 d = dg[c];
      u64 s = acc;
      u64 kc = 0;
      u64 vc = vw[c];
      #pragma unroll
      for (int g = 0; g < 8; ++g) {
        u64 dgp[8];
        #pragma unroll
        for (int j = 0; j < 8; ++j) dgp[j] = __shfl(d, g * 8 + j, 64);
        #pragma unroll
        for (int j = 0; j < 8; ++j) {
          int i = g * 8 + j;
          bool ok = !((s >> i) & 1ull) && ((vc >> i) & 1ull);
          if (ok) { s |= dgp[j]; kc |= (1ull << i); }
        }
      }
      kcw[c] = kc;
    }
    if (lane < 16) sKeep[lane] = kcw[lane];
  }
  __syncthreads();

  int total = 0;
  #pragma unroll
  for (int w = 0; w < 16; ++w) total += __popcll(sKeep[w]);
  int kept_eff = total < MAXDET ? total : MAXDET;
  float* outb = out + (size_t)b * MAXDET * 6;
  #pragma unroll
  for (int rr2 = 0; rr2 < 4; ++rr2) {
    const int t = tid + rr2 * 256;
    u64 word = sKeep[t >> 6];
    int bit = (int)((word >> (t & 63)) & 1ull);
    int rank = 0;
    for (int w = 0; w < (t >> 6); ++w) rank += __popcll(sKeep[w]);
    rank += __popcll(word & ((1ull << (t & 63)) - 1ull));
    if (bit && rank < MAXDET) {
      size_t g = (size_t)b * KCAND + t;
      float4 bx = ((const float4*)candBox)[g];
      float sc = candScore[g];
      float cf = (float)candCls[g];
      float* o = outb + (size_t)rank * 6;
      o[0] = bx.x; o[1] = bx.y; o[2] = bx.z; o[3] = bx.w; o[4] = sc; o[5] = cf;
    }
    if (t < MAXDET && t >= kept_eff) {
      float* o = outb + (size_t)t * 6;
      o[0] = 0.f; o[1] = 0.f; o[2] = 0.f; o[3] = 0.f; o[4] = 0.f; o[5] = 0.f;
    }
  }
}

extern "C" void kernel_launch(void* const* d_in, const int* in_sizes, int n_in,
                              void* d_out, int out_size, void* d_ws, size_t ws_size,
                              hipStream_t stream) {
  const float* pred = (const float*)d_in[0];
  float* out = (float*)d_out;
  char* ws = (char*)d_ws;
  size_t o = 0;
  float* masked    = (float*)(ws + o); o += (size_t)BB * NN * 4;
  int*   clsArr    = (int*)  (ws + o); o += (size_t)BB * NN * 4;
  float* candScore = (float*)(ws + o); o += (size_t)BB * KCAND * 4;
  float* candBox   = (float*)(ws + o); o += (size_t)BB * KCAND * 16;
  int*   candCls   = (int*)  (ws + o); o += (size_t)BB * KCAND * 4;
  o = (o + 255) & ~(size_t)255;
  u64*   matT      = (u64*)  (ws + o); o += (size_t)BB * KCAND * 16 * 8; // 2 MB
  u32*   hist      = (u32*)  (ws + o); o += (size_t)BB * NHBIN * 4;      // 4 MB

  const int rows = BB * NN;                 // 403200, divisible by 64
  k_zero<<<256, 1024, 0, stream>>>((uint4*)hist);
  k_score<<<rows / 64, 64, 0, stream>>>(pred, masked, clsArr, hist);
  k_select<<<BB, 1024, 0, stream>>>(pred, masked, clsArr, hist, candScore, candBox, candCls);
  k_iou<<<dim3(16, BB), 256, 0, stream>>>(candBox, candCls, matT);
  k_scan_out<<<BB, 256, 0, stream>>>(matT, candScore, candBox, candCls, out);
}